// Round 7
// baseline (311.780 us; speedup 1.0000x reference)
//
#include <hip/hip_runtime.h>
#include <math.h>
#include <stdint.h>

#define NN   50000
#define NPAD 50048          // 391 * 128
#define CD   256
#define DEG  16

typedef _Float16 f16;
typedef _Float16 f16x2 __attribute__((ext_vector_type(2)));
typedef _Float16 f16x4 __attribute__((ext_vector_type(4)));
typedef _Float16 f16x8 __attribute__((ext_vector_type(8)));
typedef float    f32x4 __attribute__((ext_vector_type(4)));

typedef const uint32_t __attribute__((address_space(1)))* gptr_t;
typedef uint32_t       __attribute__((address_space(3)))* lptr_t;

// Head-major layout for Q,K,V: elem(h, n, d) = (h*NPAD + n)*32 + d

// ---------------------------------------------------------------------------
// h (f32) -> h16 (f16), zero-padded rows up to NPAD
// ---------------------------------------------------------------------------
__global__ __launch_bounds__(256) void conv_h(const float* __restrict__ h,
                                              f16* __restrict__ o)
{
    size_t i8 = ((size_t)blockIdx.x * 256 + threadIdx.x) * 8;
    if (i8 >= (size_t)NPAD * CD) return;
    f16x8 r;
    if (i8 < (size_t)NN * CD) {
        float4 a = ((const float4*)(h + i8))[0];
        float4 b = ((const float4*)(h + i8))[1];
        r[0] = (f16)a.x; r[1] = (f16)a.y; r[2] = (f16)a.z; r[3] = (f16)a.w;
        r[4] = (f16)b.x; r[5] = (f16)b.y; r[6] = (f16)b.z; r[7] = (f16)b.w;
    } else {
        r = (f16x8)(f16)0.f;
    }
    *(f16x8*)(o + i8) = r;
}

// ---------------------------------------------------------------------------
// W (f32 [k][n]) -> Wt (f16 [n][k]) for each of the 3 matrices
// ---------------------------------------------------------------------------
__global__ __launch_bounds__(256) void conv_w(const float* __restrict__ Wq,
                                              const float* __restrict__ Wk,
                                              const float* __restrict__ Wv,
                                              f16* __restrict__ Wt)
{
    const float* W = (blockIdx.y == 0) ? Wq : (blockIdx.y == 1) ? Wk : Wv;
    int n = blockIdx.x, k = threadIdx.x;
    Wt[(size_t)blockIdx.y * 65536 + n * 256 + k] = (f16)W[k * 256 + n];
}

// ---------------------------------------------------------------------------
// Q|K|V = h16 @ W   via mfma_f32_16x16x32_f16.
// Tile 128(M) x 256(N, full width) per block, BK=64, K=256 -> 4 steps.
// grid (391, 3): z = matrix. A staged once per (tile,z) instead of twice.
// LDS 48 KB: A[128][64] f16 (16K) + B[256][64] f16 (32K), XOR slot swizzle
// via pre-swizzled global source (linear LDS dest) + swizzled ds_read.
// 4 waves; wave = all 128 rows x 64 cols (wn = wid*64): acc[8][4].
// ---------------------------------------------------------------------------
__global__ __launch_bounds__(256) void gemm16(
    const f16* __restrict__ h16, const f16* __restrict__ Wt,
    f16* __restrict__ Qo, f16* __restrict__ Ko, f16* __restrict__ Vo)
{
    __shared__ __align__(16) char lds[49152];   // A: [0,16K) B: [16K,48K)

    const int t    = threadIdx.x;
    const int lane = t & 63;
    const int wid  = t >> 6;
    const int tm   = blockIdx.x;
    const int z    = blockIdx.y;

    const f16* B = Wt + (size_t)z * 65536;
    f16* O = (z == 0) ? Qo : (z == 1) ? Ko : Vo;

    const int r15 = lane & 15;
    const int g4  = lane >> 4;
    const int l7  = lane & 7;
    const int wn  = wid * 64;                 // wave's 64-col slice of N=256

    f32x4 acc[8][4];
#pragma unroll
    for (int i = 0; i < 8; ++i)
#pragma unroll
        for (int j = 0; j < 4; ++j) acc[i][j] = (f32x4)0.f;

    for (int kb = 0; kb < 4; ++kb) {
        // ---- stage A (4 iters) + B (8 iters); swizzled source, linear dest
#pragma unroll
        for (int i = 0; i < 4; ++i) {
            int L    = i * 256 + t;
            int row  = L >> 3;                    // 0..127
            int slot = (L & 7) ^ (row & 7);
            const char* srcA = (const char*)h16 +
                ((size_t)(tm * 128 + row)) * 512 + kb * 128 + slot * 16;
            uint32_t ldsOff = (uint32_t)(i * 256 + (t & 192)) * 16;
            __builtin_amdgcn_global_load_lds((gptr_t)srcA, (lptr_t)(lds + ldsOff), 16, 0, 0);
        }
#pragma unroll
        for (int i = 0; i < 8; ++i) {
            int L    = i * 256 + t;
            int row  = L >> 3;                    // 0..255
            int slot = (L & 7) ^ (row & 7);
            const char* srcB = (const char*)B +
                ((size_t)row) * 512 + kb * 128 + slot * 16;
            uint32_t ldsOff = (uint32_t)(i * 256 + (t & 192)) * 16;
            __builtin_amdgcn_global_load_lds((gptr_t)srcB, (lptr_t)(lds + 16384 + ldsOff), 16, 0, 0);
        }
        __syncthreads();                          // drains vmcnt before barrier

        // ---- compute ----
#pragma unroll
        for (int ks = 0; ks < 2; ++ks) {
            const int sl = (ks * 4 + g4) ^ l7;    // swizzled read slot
            f16x8 a[8], b[4];
#pragma unroll
            for (int am = 0; am < 8; ++am) {
                int row = am * 16 + r15;          // all 128 A rows per wave
                a[am] = *(const f16x8*)(lds + row * 128 + sl * 16);
            }
#pragma unroll
            for (int bn = 0; bn < 4; ++bn) {
                int row = wn + bn * 16 + r15;     // 0..255
                b[bn] = *(const f16x8*)(lds + 16384 + row * 128 + sl * 16);
            }
#pragma unroll
            for (int am = 0; am < 8; ++am)
#pragma unroll
                for (int bn = 0; bn < 4; ++bn)
                    acc[am][bn] = __builtin_amdgcn_mfma_f32_16x16x32_f16(
                        a[am], b[bn], acc[am][bn], 0, 0, 0);
        }
        if (kb < 3) __syncthreads();              // protect LDS before restage
    }

    // ---- epilogue: C row = (lane>>4)*4 + reg, col = lane&15; head-major out
#pragma unroll
    for (int am = 0; am < 8; ++am) {
#pragma unroll
        for (int bn = 0; bn < 4; ++bn) {
            int col = wn + bn * 16 + r15;         // 0..255
            int hh  = col >> 5, dd = col & 31;
#pragma unroll
            for (int j = 0; j < 4; ++j) {
                int gm = tm * 128 + am * 16 + g4 * 4 + j;
                if (gm < NN)
                    O[((size_t)hh * NPAD + gm) * 32 + dd] = (f16)acc[am][bn][j];
            }
        }
    }
}

// ---------------------------------------------------------------------------
// 2D RoPE in-place on head-major f16 Q,K. grid (ceil(NN/256), 8). (unchanged)
// ---------------------------------------------------------------------------
__global__ __launch_bounds__(256) void rope16(const float* __restrict__ pos,
                                              f16* __restrict__ Q,
                                              f16* __restrict__ K)
{
    int n = blockIdx.x * 256 + threadIdx.x;
    if (n >= NN) return;
    int hd = blockIdx.y;

    float cx = pos[2 * n] * 64.f;
    float cy = pos[2 * n + 1] * 64.f;
    size_t base = ((size_t)hd * NPAD + n) * 32;

    union U { f16 h[32]; float4 v[4]; } q, k;
#pragma unroll
    for (int i = 0; i < 4; ++i) {
        q.v[i] = ((const float4*)(Q + base))[i];
        k.v[i] = ((const float4*)(K + base))[i];
    }

    const float INVF[8] = {1.f, 0.31622776601683794f, 0.1f, 0.031622776601683794f,
                           0.01f, 0.0031622776601683794f, 0.001f, 0.00031622776601683794f};
#pragma unroll
    for (int j = 0; j < 8; ++j) {
        float sx, cxs, sy, cys;
        __sincosf(cx * INVF[j], &sx, &cxs);
        __sincosf(cy * INVF[j], &sy, &cys);
        float a, b;
        a = (float)q.h[j];      b = (float)q.h[j + 8];
        q.h[j] = (f16)(a * cxs - b * sx);  q.h[j + 8] = (f16)(b * cxs + a * sx);
        a = (float)k.h[j];      b = (float)k.h[j + 8];
        k.h[j] = (f16)(a * cxs - b * sx);  k.h[j + 8] = (f16)(b * cxs + a * sx);
        a = (float)q.h[16 + j]; b = (float)q.h[24 + j];
        q.h[16 + j] = (f16)(a * cys - b * sy);  q.h[24 + j] = (f16)(b * cys + a * sy);
        a = (float)k.h[16 + j]; b = (float)k.h[24 + j];
        k.h[16 + j] = (f16)(a * cys - b * sy);  k.h[24 + j] = (f16)(b * cys + a * sy);
    }

#pragma unroll
    for (int i = 0; i < 4; ++i) {
        ((float4*)(Q + base))[i] = q.v[i];
        ((float4*)(K + base))[i] = k.v[i];
    }
}

// ---------------------------------------------------------------------------
// scoreK: one WAVE per (node, head); lane = (edge j = l>>2, piece p = l&3).
// (unchanged from round 6)
// ---------------------------------------------------------------------------
__global__ __launch_bounds__(256) void scoreK(
    const f16* __restrict__ Q, const f16* __restrict__ K,
    const int* __restrict__ src, float* __restrict__ scores)
{
    const int tid = threadIdx.x;
    const int h   = blockIdx.y;
    const int n   = blockIdx.x * 4 + (tid >> 6);    // 12500*4 = 50000
    const int l   = tid & 63;
    const int j   = l >> 2;                         // edge 0..15
    const int p   = l & 3;                          // 16B piece 0..3

    const int s = src[n * DEG + j];

    f16x8 q8 = *(const f16x8*)(Q + ((size_t)h * NPAD + n) * 32 + p * 8);
    f16x8 k8 = *(const f16x8*)(K + ((size_t)h * NPAD + s) * 32 + p * 8);

    const f16x2* qp = (const f16x2*)&q8;
    const f16x2* kp = (const f16x2*)&k8;
    float d = 0.f;
#if __has_builtin(__builtin_amdgcn_fdot2)
    d = __builtin_amdgcn_fdot2(qp[0], kp[0], d, false);
    d = __builtin_amdgcn_fdot2(qp[1], kp[1], d, false);
    d = __builtin_amdgcn_fdot2(qp[2], kp[2], d, false);
    d = __builtin_amdgcn_fdot2(qp[3], kp[3], d, false);
#else
#pragma unroll
    for (int u = 0; u < 4; ++u)
        d += (float)qp[u].x * (float)kp[u].x + (float)qp[u].y * (float)kp[u].y;
#endif

    d += __shfl_xor(d, 1);          // combine pieces within 4-lane group
    d += __shfl_xor(d, 2);

    if (p == 0)
        scores[((size_t)h * NN + n) * DEG + j] =
            __expf(fminf(fmaxf(d * 0.17677669529663687f, -5.f), 5.f));
}

// ---------------------------------------------------------------------------
// aggV: per (node, head): out = sum_j w_j * V_h[src_j] / sum_j w_j.
// grid (1563, 8). lane = (node, 4-dim slice). (unchanged)
// ---------------------------------------------------------------------------
__global__ __launch_bounds__(256) void aggV(
    const f16* __restrict__ V, const int* __restrict__ src,
    const float* __restrict__ scores, float* __restrict__ out)
{
    const int tid = threadIdx.x;
    const int h   = blockIdx.y;
    const int g   = blockIdx.x * 256 + tid;
    const int n   = g >> 3;
    const int ln  = g & 7;
    if (n >= NN) return;

    const float4* S4 = (const float4*)(scores + ((size_t)h * NN + n) * DEG);
    float4 s0 = S4[0], s1 = S4[1], s2 = S4[2], s3 = S4[3];
    float w[16] = {s0.x, s0.y, s0.z, s0.w, s1.x, s1.y, s1.z, s1.w,
                   s2.x, s2.y, s2.z, s2.w, s3.x, s3.y, s3.z, s3.w};

    const int4* SR = (const int4*)(src + n * DEG);
    int4 r0 = SR[0], r1 = SR[1], r2 = SR[2], r3 = SR[3];
    int sj[16] = {r0.x, r0.y, r0.z, r0.w, r1.x, r1.y, r1.z, r1.w,
                  r2.x, r2.y, r2.z, r2.w, r3.x, r3.y, r3.z, r3.w};

    float z = 0.f;
#pragma unroll
    for (int j = 0; j < DEG; ++j) z += w[j];

    float a0 = 0.f, a1 = 0.f, a2 = 0.f, a3 = 0.f;
#pragma unroll
    for (int j = 0; j < DEG; ++j) {
        f16x4 v4 = *(const f16x4*)(V + ((size_t)h * NPAD + sj[j]) * 32 + ln * 4);
        a0 += w[j] * (float)v4[0];
        a1 += w[j] * (float)v4[1];
        a2 += w[j] * (float)v4[2];
        a3 += w[j] * (float)v4[3];
    }
    float rz = 1.f / z;
    float4 o;
    o.x = a0 * rz; o.y = a1 * rz; o.z = a2 * rz; o.w = a3 * rz;
    *(float4*)(out + (size_t)n * CD + h * 32 + ln * 4) = o;
}

// ---------------------------------------------------------------------------
extern "C" void kernel_launch(void* const* d_in, const int* in_sizes, int n_in,
                              void* d_out, int out_size, void* d_ws, size_t ws_size,
                              hipStream_t stream)
{
    const float* h   = (const float*)d_in[0];
    const float* pos = (const float*)d_in[1];
    const float* Wq  = (const float*)d_in[2];
    const float* Wk  = (const float*)d_in[3];
    const float* Wv  = (const float*)d_in[4];
    const int*   src = (const int*)d_in[5];
    float* out = (float*)d_out;

    char* w = (char*)d_ws;
    f16*   h16    = (f16*)w;                              // 25,624,576 B
    float* scores = (float*)w;                            // reuses h16 (dead after gemm16)
    f16*   Wt     = (f16*)(w + 25624576);                 //    393,216 B
    f16*   Qb     = (f16*)(w + 26017792);                 // 25,624,576 B
    f16*   Kb     = (f16*)(w + 51642368);
    f16*   Vb     = (f16*)(w + 77266944);                 // end ~98.1 MiB

    conv_h<<<(NPAD * CD / 8 + 255) / 256, 256, 0, stream>>>(h, h16);
    conv_w<<<dim3(256, 3), 256, 0, stream>>>(Wq, Wk, Wv, Wt);
    gemm16<<<dim3(391, 3), 256, 0, stream>>>(h16, Wt, Qb, Kb, Vb);
    rope16<<<dim3((NN + 255) / 256, 8), 256, 0, stream>>>(pos, Qb, Kb);
    scoreK<<<dim3(12500, 8), 256, 0, stream>>>(Qb, Kb, src, scores);
    aggV<<<dim3(1563, 8), 256, 0, stream>>>(Vb, src, scores, out);
}

// Round 8
// 304.724 us; speedup vs baseline: 1.0232x; 1.0232x over previous
//
#include <hip/hip_runtime.h>
#include <math.h>
#include <stdint.h>

#define NN   50000
#define NPAD 50048          // 391 * 128
#define CD   256
#define DEG  16

typedef _Float16 f16;
typedef _Float16 f16x2 __attribute__((ext_vector_type(2)));
typedef _Float16 f16x4 __attribute__((ext_vector_type(4)));
typedef _Float16 f16x8 __attribute__((ext_vector_type(8)));
typedef float    f32x4 __attribute__((ext_vector_type(4)));

typedef const uint32_t __attribute__((address_space(1)))* gptr_t;
typedef uint32_t       __attribute__((address_space(3)))* lptr_t;

// Head-major layout for Q,K,V: elem(h, n, d) = (h*NPAD + n)*32 + d

#define CONVH_BLOCKS 6256   // NPAD*CD/8/256

// ---------------------------------------------------------------------------
// Fused conversion kernel: blocks [0, CONVH_BLOCKS) convert h -> f16 (padded);
// blocks [CONVH_BLOCKS, +768) transpose W -> Wt f16 [n][k].
// ---------------------------------------------------------------------------
__global__ __launch_bounds__(256) void conv_hw(
    const float* __restrict__ h,
    const float* __restrict__ Wq, const float* __restrict__ Wk,
    const float* __restrict__ Wv,
    f16* __restrict__ o, f16* __restrict__ Wt)
{
    int b = blockIdx.x;
    if (b < CONVH_BLOCKS) {
        size_t i8 = ((size_t)b * 256 + threadIdx.x) * 8;
        if (i8 >= (size_t)NPAD * CD) return;
        f16x8 r;
        if (i8 < (size_t)NN * CD) {
            float4 a = ((const float4*)(h + i8))[0];
            float4 c = ((const float4*)(h + i8))[1];
            r[0] = (f16)a.x; r[1] = (f16)a.y; r[2] = (f16)a.z; r[3] = (f16)a.w;
            r[4] = (f16)c.x; r[5] = (f16)c.y; r[6] = (f16)c.z; r[7] = (f16)c.w;
        } else {
            r = (f16x8)(f16)0.f;
        }
        *(f16x8*)(o + i8) = r;
    } else {
        int bb = b - CONVH_BLOCKS;          // 0..767
        int m  = bb >> 8;                   // matrix 0..2
        int n  = bb & 255;
        const float* W = (m == 0) ? Wq : (m == 1) ? Wk : Wv;
        int k = threadIdx.x;
        Wt[(size_t)m * 65536 + n * 256 + k] = (f16)W[k * 256 + n];
    }
}

// ---------------------------------------------------------------------------
// Q|K|V = h16 @ W  via mfma_f32_16x16x32_f16.  ROUND-6 structure (proven):
// tile 128x128, BK=64, grid (391, 2, 3), LDS 32KB, XOR slot swizzle via
// pre-swizzled global source + swizzled ds_read.  Head-major epilogue.
// ---------------------------------------------------------------------------
__global__ __launch_bounds__(256) void gemm16(
    const f16* __restrict__ h16, const f16* __restrict__ Wt,
    f16* __restrict__ Qo, f16* __restrict__ Ko, f16* __restrict__ Vo)
{
    __shared__ __align__(16) char lds[32768];   // A: [0,16K) B: [16K,32K)

    const int t    = threadIdx.x;
    const int lane = t & 63;
    const int wid  = t >> 6;
    const int tm   = blockIdx.x;
    const int nc0  = blockIdx.y * 128;
    const int z    = blockIdx.z;

    const f16* B = Wt + (size_t)z * 65536;
    f16* O = (z == 0) ? Qo : (z == 1) ? Ko : Vo;

    const int r15 = lane & 15;
    const int g4  = lane >> 4;
    const int l7  = lane & 7;
    const int wm  = (wid >> 1) * 64;
    const int wn  = (wid & 1) * 64;

    f32x4 acc[4][4];
#pragma unroll
    for (int i = 0; i < 4; ++i)
#pragma unroll
        for (int j = 0; j < 4; ++j) acc[i][j] = (f32x4)0.f;

    for (int kb = 0; kb < 4; ++kb) {
        // ---- stage A,B tiles (swizzled source, linear LDS dest) ----
#pragma unroll
        for (int i = 0; i < 4; ++i) {
            int L    = i * 256 + t;
            int row  = L >> 3;                    // 0..127
            int slot = (L & 7) ^ (row & 7);       // source slot
            const char* srcA = (const char*)h16 +
                ((size_t)(tm * 128 + row)) * 512 + kb * 128 + slot * 16;
            const char* srcB = (const char*)B +
                ((size_t)(nc0 + row)) * 512 + kb * 128 + slot * 16;
            uint32_t ldsOff = (uint32_t)(i * 256 + (t & 192)) * 16;
            __builtin_amdgcn_global_load_lds((gptr_t)srcA, (lptr_t)(lds + ldsOff), 16, 0, 0);
            __builtin_amdgcn_global_load_lds((gptr_t)srcB, (lptr_t)(lds + 16384 + ldsOff), 16, 0, 0);
        }
        __syncthreads();                          // drains vmcnt before barrier

        // ---- compute ----
#pragma unroll
        for (int ks = 0; ks < 2; ++ks) {
            const int sl = (ks * 4 + g4) ^ l7;    // swizzled read slot
            f16x8 a[4], b[4];
#pragma unroll
            for (int am = 0; am < 4; ++am) {
                int row = wm + am * 16 + r15;
                a[am] = *(const f16x8*)(lds + row * 128 + sl * 16);
            }
#pragma unroll
            for (int bn = 0; bn < 4; ++bn) {
                int row = wn + bn * 16 + r15;
                b[bn] = *(const f16x8*)(lds + 16384 + row * 128 + sl * 16);
            }
#pragma unroll
            for (int am = 0; am < 4; ++am)
#pragma unroll
                for (int bn = 0; bn < 4; ++bn)
                    acc[am][bn] = __builtin_amdgcn_mfma_f32_16x16x32_f16(
                        a[am], b[bn], acc[am][bn], 0, 0, 0);
        }
        if (kb < 3) __syncthreads();              // protect LDS before restage
    }

    // ---- epilogue: C row = (lane>>4)*4 + reg, col = lane&15; head-major out
#pragma unroll
    for (int am = 0; am < 4; ++am) {
#pragma unroll
        for (int bn = 0; bn < 4; ++bn) {
            int col = nc0 + wn + bn * 16 + r15;   // 0..255
            int hh  = col >> 5, dd = col & 31;
#pragma unroll
            for (int j = 0; j < 4; ++j) {
                int gm = tm * 128 + wm + am * 16 + g4 * 4 + j;
                if (gm < NN)
                    O[((size_t)hh * NPAD + gm) * 32 + dd] = (f16)acc[am][bn][j];
            }
        }
    }
}

// ---------------------------------------------------------------------------
// 2D RoPE in-place on head-major f16 Q,K. grid (ceil(NN/256), 8). (unchanged)
// ---------------------------------------------------------------------------
__global__ __launch_bounds__(256) void rope16(const float* __restrict__ pos,
                                              f16* __restrict__ Q,
                                              f16* __restrict__ K)
{
    int n = blockIdx.x * 256 + threadIdx.x;
    if (n >= NN) return;
    int hd = blockIdx.y;

    float cx = pos[2 * n] * 64.f;
    float cy = pos[2 * n + 1] * 64.f;
    size_t base = ((size_t)hd * NPAD + n) * 32;

    union U { f16 h[32]; float4 v[4]; } q, k;
#pragma unroll
    for (int i = 0; i < 4; ++i) {
        q.v[i] = ((const float4*)(Q + base))[i];
        k.v[i] = ((const float4*)(K + base))[i];
    }

    const float INVF[8] = {1.f, 0.31622776601683794f, 0.1f, 0.031622776601683794f,
                           0.01f, 0.0031622776601683794f, 0.001f, 0.00031622776601683794f};
#pragma unroll
    for (int j = 0; j < 8; ++j) {
        float sx, cxs, sy, cys;
        __sincosf(cx * INVF[j], &sx, &cxs);
        __sincosf(cy * INVF[j], &sy, &cys);
        float a, b;
        a = (float)q.h[j];      b = (float)q.h[j + 8];
        q.h[j] = (f16)(a * cxs - b * sx);  q.h[j + 8] = (f16)(b * cxs + a * sx);
        a = (float)k.h[j];      b = (float)k.h[j + 8];
        k.h[j] = (f16)(a * cxs - b * sx);  k.h[j + 8] = (f16)(b * cxs + a * sx);
        a = (float)q.h[16 + j]; b = (float)q.h[24 + j];
        q.h[16 + j] = (f16)(a * cys - b * sy);  q.h[24 + j] = (f16)(b * cys + a * sy);
        a = (float)k.h[16 + j]; b = (float)k.h[24 + j];
        k.h[16 + j] = (f16)(a * cys - b * sy);  k.h[24 + j] = (f16)(b * cys + a * sy);
    }

#pragma unroll
    for (int i = 0; i < 4; ++i) {
        ((float4*)(Q + base))[i] = q.v[i];
        ((float4*)(K + base))[i] = k.v[i];
    }
}

// ---------------------------------------------------------------------------
// scoreK v3 (MFMA): one wave per (node, head).
// A-frag: 16 gathered K rows — lane: row j = l&15, k-octet kc = l>>4
//         (A row=lane&15, k=(lane>>4)*8+r — verified layout from gemm16).
// B-frag: Q[n] broadcast to all 16 cols — lane loads Q[n][kc*8..+8]
//         (B col=lane&15, k=(lane>>4)*8+r; load is col-independent).
// C: score_j = C[j][any col]; lane group kc holds rows kc*4..+4 in c[0..3].
// All lanes compute exp (cols duplicated); lanes with j==0 store float4.
// No LDS, no barriers, no shuffles.  grid (12500, 8).
// ---------------------------------------------------------------------------
__global__ __launch_bounds__(256) void scoreK(
    const f16* __restrict__ Q, const f16* __restrict__ K,
    const int* __restrict__ src, float* __restrict__ scores)
{
    const int tid = threadIdx.x;
    const int h   = blockIdx.y;
    const int n   = blockIdx.x * 4 + (tid >> 6);    // 12500*4 = 50000
    const int l   = tid & 63;
    const int j   = l & 15;                         // A row = edge index
    const int kc  = l >> 4;                         // k-octet 0..3

    const int s = src[n * DEG + j];

    f16x8 a = *(const f16x8*)(K + ((size_t)h * NPAD + s) * 32 + kc * 8);
    f16x8 b = *(const f16x8*)(Q + ((size_t)h * NPAD + n) * 32 + kc * 8);

    f32x4 c = (f32x4)0.f;
    c = __builtin_amdgcn_mfma_f32_16x16x32_f16(a, b, c, 0, 0, 0);

    const float SCL = 0.17677669529663687f;
    float4 e;
    e.x = __expf(fminf(fmaxf(c[0] * SCL, -5.f), 5.f));
    e.y = __expf(fminf(fmaxf(c[1] * SCL, -5.f), 5.f));
    e.z = __expf(fminf(fmaxf(c[2] * SCL, -5.f), 5.f));
    e.w = __expf(fminf(fmaxf(c[3] * SCL, -5.f), 5.f));

    if (j == 0)   // lanes 0,16,32,48: rows kc*4 .. kc*4+3
        *(float4*)(scores + ((size_t)h * NN + n) * DEG + kc * 4) = e;
}

// ---------------------------------------------------------------------------
// aggV: per (node, head): out = sum_j w_j * V_h[src_j] / sum_j w_j.
// grid (1563, 8). lane = (node, 4-dim slice). (unchanged)
// ---------------------------------------------------------------------------
__global__ __launch_bounds__(256) void aggV(
    const f16* __restrict__ V, const int* __restrict__ src,
    const float* __restrict__ scores, float* __restrict__ out)
{
    const int tid = threadIdx.x;
    const int h   = blockIdx.y;
    const int g   = blockIdx.x * 256 + tid;
    const int n   = g >> 3;
    const int ln  = g & 7;
    if (n >= NN) return;

    const float4* S4 = (const float4*)(scores + ((size_t)h * NN + n) * DEG);
    float4 s0 = S4[0], s1 = S4[1], s2 = S4[2], s3 = S4[3];
    float w[16] = {s0.x, s0.y, s0.z, s0.w, s1.x, s1.y, s1.z, s1.w,
                   s2.x, s2.y, s2.z, s2.w, s3.x, s3.y, s3.z, s3.w};

    const int4* SR = (const int4*)(src + n * DEG);
    int4 r0 = SR[0], r1 = SR[1], r2 = SR[2], r3 = SR[3];
    int sj[16] = {r0.x, r0.y, r0.z, r0.w, r1.x, r1.y, r1.z, r1.w,
                  r2.x, r2.y, r2.z, r2.w, r3.x, r3.y, r3.z, r3.w};

    float z = 0.f;
#pragma unroll
    for (int j = 0; j < DEG; ++j) z += w[j];

    float a0 = 0.f, a1 = 0.f, a2 = 0.f, a3 = 0.f;
#pragma unroll
    for (int j = 0; j < DEG; ++j) {
        f16x4 v4 = *(const f16x4*)(V + ((size_t)h * NPAD + sj[j]) * 32 + ln * 4);
        a0 += w[j] * (float)v4[0];
        a1 += w[j] * (float)v4[1];
        a2 += w[j] * (float)v4[2];
        a3 += w[j] * (float)v4[3];
    }
    float rz = 1.f / z;
    float4 o;
    o.x = a0 * rz; o.y = a1 * rz; o.z = a2 * rz; o.w = a3 * rz;
    *(float4*)(out + (size_t)n * CD + h * 32 + ln * 4) = o;
}

// ---------------------------------------------------------------------------
extern "C" void kernel_launch(void* const* d_in, const int* in_sizes, int n_in,
                              void* d_out, int out_size, void* d_ws, size_t ws_size,
                              hipStream_t stream)
{
    const float* h   = (const float*)d_in[0];
    const float* pos = (const float*)d_in[1];
    const float* Wq  = (const float*)d_in[2];
    const float* Wk  = (const float*)d_in[3];
    const float* Wv  = (const float*)d_in[4];
    const int*   src = (const int*)d_in[5];
    float* out = (float*)d_out;

    char* w = (char*)d_ws;
    f16*   h16    = (f16*)w;                              // 25,624,576 B
    float* scores = (float*)w;                            // reuses h16 (dead after gemm16)
    f16*   Wt     = (f16*)(w + 25624576);                 //    393,216 B
    f16*   Qb     = (f16*)(w + 26017792);                 // 25,624,576 B
    f16*   Kb     = (f16*)(w + 51642368);
    f16*   Vb     = (f16*)(w + 77266944);                 // end ~98.1 MiB

    conv_hw<<<CONVH_BLOCKS + 768, 256, 0, stream>>>(h, Wq, Wk, Wv, h16, Wt);
    gemm16<<<dim3(391, 2, 3), 256, 0, stream>>>(h16, Wt, Qb, Kb, Vb);
    rope16<<<dim3((NN + 255) / 256, 8), 256, 0, stream>>>(pos, Qb, Kb);
    scoreK<<<dim3(12500, 8), 256, 0, stream>>>(Qb, Kb, src, scores);
    aggV<<<dim3(1563, 8), 256, 0, stream>>>(Vb, src, scores, out);
}

// Round 10
// 267.524 us; speedup vs baseline: 1.1654x; 1.1391x over previous
//
#include <hip/hip_runtime.h>
#include <math.h>
#include <stdint.h>

#define NN   50000
#define NPAD 50048          // 391 * 128
#define CD   256
#define DEG  16

typedef _Float16 f16;
typedef _Float16 f16x2 __attribute__((ext_vector_type(2)));
typedef _Float16 f16x4 __attribute__((ext_vector_type(4)));
typedef _Float16 f16x8 __attribute__((ext_vector_type(8)));
typedef float    f32x4 __attribute__((ext_vector_type(4)));

typedef const uint32_t __attribute__((address_space(1)))* gptr_t;
typedef uint32_t       __attribute__((address_space(3)))* lptr_t;

// Head-major layout for Q,K,V: elem(h, n, d) = (h*NPAD + n)*32 + d

#define CONVH_BLOCKS 6256   // NPAD*CD/8/256

// ---------------------------------------------------------------------------
// Fused conversion kernel: blocks [0, CONVH_BLOCKS) convert h -> f16 (padded);
// blocks [CONVH_BLOCKS, +768) transpose W -> Wt f16 [n][k].
// ---------------------------------------------------------------------------
__global__ __launch_bounds__(256) void conv_hw(
    const float* __restrict__ h,
    const float* __restrict__ Wq, const float* __restrict__ Wk,
    const float* __restrict__ Wv,
    f16* __restrict__ o, f16* __restrict__ Wt)
{
    int b = blockIdx.x;
    if (b < CONVH_BLOCKS) {
        size_t i8 = ((size_t)b * 256 + threadIdx.x) * 8;
        if (i8 >= (size_t)NPAD * CD) return;
        f16x8 r;
        if (i8 < (size_t)NN * CD) {
            float4 a = ((const float4*)(h + i8))[0];
            float4 c = ((const float4*)(h + i8))[1];
            r[0] = (f16)a.x; r[1] = (f16)a.y; r[2] = (f16)a.z; r[3] = (f16)a.w;
            r[4] = (f16)c.x; r[5] = (f16)c.y; r[6] = (f16)c.z; r[7] = (f16)c.w;
        } else {
            r = (f16x8)(f16)0.f;
        }
        *(f16x8*)(o + i8) = r;
    } else {
        int bb = b - CONVH_BLOCKS;          // 0..767
        int m  = bb >> 8;                   // matrix 0..2
        int n  = bb & 255;
        const float* W = (m == 0) ? Wq : (m == 1) ? Wk : Wv;
        int k = threadIdx.x;
        Wt[(size_t)m * 65536 + n * 256 + k] = (f16)W[k * 256 + n];
    }
}

// ---------------------------------------------------------------------------
// Q|K|V = h16 @ W  via mfma_f32_16x16x32_f16.  Round-6 GEMM structure
// (proven fastest): tile 128x128, BK=64, grid (391, 2, 3), LDS 32KB,
// XOR slot swizzle.  RoPE fused into the epilogue for z<2 (Q,K):
//   pair (d, d+8) lives at lane r15^8 of the same acc element ->
//   one shfl_xor(8); freq idx = r15&7; x/y half = dd&16;
//   sign = (r15>=8) ? + : -.   V (z=2) stored unrotated.
// ---------------------------------------------------------------------------
__global__ __launch_bounds__(256) void gemm16(
    const f16* __restrict__ h16, const f16* __restrict__ Wt,
    const float* __restrict__ pos,
    f16* __restrict__ Qo, f16* __restrict__ Ko, f16* __restrict__ Vo)
{
    __shared__ __align__(16) char lds[32768];   // A: [0,16K) B: [16K,32K)

    const int t    = threadIdx.x;
    const int lane = t & 63;
    const int wid  = t >> 6;
    const int tm   = blockIdx.x;
    const int nc0  = blockIdx.y * 128;
    const int z    = blockIdx.z;

    const f16* B = Wt + (size_t)z * 65536;
    f16* O = (z == 0) ? Qo : (z == 1) ? Ko : Vo;

    const int r15 = lane & 15;
    const int g4  = lane >> 4;
    const int l7  = lane & 7;
    const int wm  = (wid >> 1) * 64;
    const int wn  = (wid & 1) * 64;

    f32x4 acc[4][4];
#pragma unroll
    for (int i = 0; i < 4; ++i)
#pragma unroll
        for (int j = 0; j < 4; ++j) acc[i][j] = (f32x4)0.f;

    for (int kb = 0; kb < 4; ++kb) {
        // ---- stage A,B tiles (swizzled source, linear LDS dest) ----
#pragma unroll
        for (int i = 0; i < 4; ++i) {
            int L    = i * 256 + t;
            int row  = L >> 3;                    // 0..127
            int slot = (L & 7) ^ (row & 7);       // source slot
            const char* srcA = (const char*)h16 +
                ((size_t)(tm * 128 + row)) * 512 + kb * 128 + slot * 16;
            const char* srcB = (const char*)B +
                ((size_t)(nc0 + row)) * 512 + kb * 128 + slot * 16;
            uint32_t ldsOff = (uint32_t)(i * 256 + (t & 192)) * 16;
            __builtin_amdgcn_global_load_lds((gptr_t)srcA, (lptr_t)(lds + ldsOff), 16, 0, 0);
            __builtin_amdgcn_global_load_lds((gptr_t)srcB, (lptr_t)(lds + 16384 + ldsOff), 16, 0, 0);
        }
        __syncthreads();                          // drains vmcnt before barrier

        // ---- compute ----
#pragma unroll
        for (int ks = 0; ks < 2; ++ks) {
            const int sl = (ks * 4 + g4) ^ l7;    // swizzled read slot
            f16x8 a[4], b[4];
#pragma unroll
            for (int am = 0; am < 4; ++am) {
                int row = wm + am * 16 + r15;
                a[am] = *(const f16x8*)(lds + row * 128 + sl * 16);
            }
#pragma unroll
            for (int bn = 0; bn < 4; ++bn) {
                int row = wn + bn * 16 + r15;
                b[bn] = *(const f16x8*)(lds + 16384 + row * 128 + sl * 16);
            }
#pragma unroll
            for (int am = 0; am < 4; ++am)
#pragma unroll
                for (int bn = 0; bn < 4; ++bn)
                    acc[am][bn] = __builtin_amdgcn_mfma_f32_16x16x32_f16(
                        a[am], b[bn], acc[am][bn], 0, 0, 0);
        }
        if (kb < 3) __syncthreads();              // protect LDS before restage
    }

    // ---- epilogue: C row = (lane>>4)*4 + reg, col = lane&15; head-major out
    const float INVF[8] = {1.f, 0.31622776601683794f, 0.1f, 0.031622776601683794f,
                           0.01f, 0.0031622776601683794f, 0.001f, 0.00031622776601683794f};
    const float invf = INVF[l7] * 64.f;
    const bool  hi   = (r15 & 8) != 0;

#pragma unroll
    for (int am = 0; am < 4; ++am) {
        if (z < 2) {
            // fused RoPE for this am's 4 rows
            float sx[4], cx[4], sy[4], cy[4];
#pragma unroll
            for (int j = 0; j < 4; ++j) {
                int gm = tm * 128 + wm + am * 16 + g4 * 4 + j;
                int gc = (gm < NN) ? gm : 0;
                float2 p = *(const float2*)(pos + 2 * gc);
                __sincosf(p.x * invf, &sx[j], &cx[j]);
                __sincosf(p.y * invf, &sy[j], &cy[j]);
            }
#pragma unroll
            for (int bn = 0; bn < 4; ++bn) {
                int col = nc0 + wn + bn * 16 + r15;   // 0..255
                int hh  = col >> 5, dd = col & 31;
                const bool yhalf = (dd & 16) != 0;
#pragma unroll
                for (int j = 0; j < 4; ++j) {
                    float v    = acc[am][bn][j];
                    float part = __shfl_xor(v, 8);
                    float c = yhalf ? cy[j] : cx[j];
                    float s = yhalf ? sy[j] : sx[j];
                    float res = hi ? (v * c + part * s) : (v * c - part * s);
                    int gm = tm * 128 + wm + am * 16 + g4 * 4 + j;
                    if (gm < NN)
                        O[((size_t)hh * NPAD + gm) * 32 + dd] = (f16)res;
                }
            }
        } else {
#pragma unroll
            for (int bn = 0; bn < 4; ++bn) {
                int col = nc0 + wn + bn * 16 + r15;
                int hh  = col >> 5, dd = col & 31;
#pragma unroll
                for (int j = 0; j < 4; ++j) {
                    int gm = tm * 128 + wm + am * 16 + g4 * 4 + j;
                    if (gm < NN)
                        O[((size_t)hh * NPAD + gm) * 32 + dd] = (f16)acc[am][bn][j];
                }
            }
        }
    }
}

// ---------------------------------------------------------------------------
// scoreK (round-6 v2 inner, fastest): one WAVE per (node, head);
// lane = (edge j = l>>2, piece p = l&3); 4 lanes per K row (16 B each);
// partial dots combined via shfl_xor(1,2).  No LDS, no barriers.
// GRID: 1-D, 100000 blocks; head = blockIdx & 7 -> XCD-pinned: XCD x
// (default round-robin blockIdx%8) only touches K_h/Q_h of head x, so the
// 3.2 MB per-head K stays resident in that XCD's 4 MB L2.
// ---------------------------------------------------------------------------
__global__ __launch_bounds__(256) void scoreK(
    const f16* __restrict__ Q, const f16* __restrict__ K,
    const int* __restrict__ src, float* __restrict__ scores)
{
    const int b   = blockIdx.x;                     // 0..99999
    const int h   = b & 7;
    const int n   = (b >> 3) * 4 + (threadIdx.x >> 6);   // 12500*4 = 50000
    const int l   = threadIdx.x & 63;
    const int j   = l >> 2;                         // edge 0..15
    const int p   = l & 3;                          // 16B piece 0..3

    const int s = src[n * DEG + j];

    f16x8 q8 = *(const f16x8*)(Q + ((size_t)h * NPAD + n) * 32 + p * 8);
    f16x8 k8 = *(const f16x8*)(K + ((size_t)h * NPAD + s) * 32 + p * 8);

    const f16x2* qp = (const f16x2*)&q8;
    const f16x2* kp = (const f16x2*)&k8;
    float d = 0.f;
#if __has_builtin(__builtin_amdgcn_fdot2)
    d = __builtin_amdgcn_fdot2(qp[0], kp[0], d, false);
    d = __builtin_amdgcn_fdot2(qp[1], kp[1], d, false);
    d = __builtin_amdgcn_fdot2(qp[2], kp[2], d, false);
    d = __builtin_amdgcn_fdot2(qp[3], kp[3], d, false);
#else
#pragma unroll
    for (int u = 0; u < 4; ++u)
        d += (float)qp[u].x * (float)kp[u].x + (float)qp[u].y * (float)kp[u].y;
#endif

    d += __shfl_xor(d, 1);          // combine pieces within 4-lane group
    d += __shfl_xor(d, 2);

    if (p == 0)
        scores[((size_t)h * NN + n) * DEG + j] =
            __expf(fminf(fmaxf(d * 0.17677669529663687f, -5.f), 5.f));
}

// ---------------------------------------------------------------------------
// aggV: per (node, head): out = sum_j w_j * V_h[src_j] / sum_j w_j.
// GRID: 1-D 12504 blocks; head = blockIdx & 7 (XCD-pinned, V_h L2-resident).
// lane = (node, 4-dim slice).
// ---------------------------------------------------------------------------
__global__ __launch_bounds__(256) void aggV(
    const f16* __restrict__ V, const int* __restrict__ src,
    const float* __restrict__ scores, float* __restrict__ out)
{
    const int b   = blockIdx.x;                 // 0..12503
    const int h   = b & 7;
    const int g   = (b >> 3) * 256 + threadIdx.x;
    const int n   = g >> 3;
    const int ln  = g & 7;
    if (n >= NN) return;

    const float4* S4 = (const float4*)(scores + ((size_t)h * NN + n) * DEG);
    float4 s0 = S4[0], s1 = S4[1], s2 = S4[2], s3 = S4[3];
    float w[16] = {s0.x, s0.y, s0.z, s0.w, s1.x, s1.y, s1.z, s1.w,
                   s2.x, s2.y, s2.z, s2.w, s3.x, s3.y, s3.z, s3.w};

    const int4* SR = (const int4*)(src + n * DEG);
    int4 r0 = SR[0], r1 = SR[1], r2 = SR[2], r3 = SR[3];
    int sj[16] = {r0.x, r0.y, r0.z, r0.w, r1.x, r1.y, r1.z, r1.w,
                  r2.x, r2.y, r2.z, r2.w, r3.x, r3.y, r3.z, r3.w};

    float z = 0.f;
#pragma unroll
    for (int j = 0; j < DEG; ++j) z += w[j];

    float a0 = 0.f, a1 = 0.f, a2 = 0.f, a3 = 0.f;
#pragma unroll
    for (int j = 0; j < DEG; ++j) {
        f16x4 v4 = *(const f16x4*)(V + ((size_t)h * NPAD + sj[j]) * 32 + ln * 4);
        a0 += w[j] * (float)v4[0];
        a1 += w[j] * (float)v4[1];
        a2 += w[j] * (float)v4[2];
        a3 += w[j] * (float)v4[3];
    }
    float rz = 1.f / z;
    float4 o;
    o.x = a0 * rz; o.y = a1 * rz; o.z = a2 * rz; o.w = a3 * rz;
    *(float4*)(out + (size_t)n * CD + h * 32 + ln * 4) = o;
}

// ---------------------------------------------------------------------------
extern "C" void kernel_launch(void* const* d_in, const int* in_sizes, int n_in,
                              void* d_out, int out_size, void* d_ws, size_t ws_size,
                              hipStream_t stream)
{
    const float* h   = (const float*)d_in[0];
    const float* pos = (const float*)d_in[1];
    const float* Wq  = (const float*)d_in[2];
    const float* Wk  = (const float*)d_in[3];
    const float* Wv  = (const float*)d_in[4];
    const int*   src = (const int*)d_in[5];
    float* out = (float*)d_out;

    char* w = (char*)d_ws;
    f16*   h16    = (f16*)w;                              // 25,624,576 B
    float* scores = (float*)w;                            // reuses h16 (dead after gemm16)
    f16*   Wt     = (f16*)(w + 25624576);                 //    393,216 B
    f16*   Qb     = (f16*)(w + 26017792);                 // 25,624,576 B
    f16*   Kb     = (f16*)(w + 51642368);
    f16*   Vb     = (f16*)(w + 77266944);                 // end ~98.1 MiB

    conv_hw<<<CONVH_BLOCKS + 768, 256, 0, stream>>>(h, Wq, Wk, Wv, h16, Wt);
    gemm16<<<dim3(391, 2, 3), 256, 0, stream>>>(h16, Wt, pos, Qb, Kb, Vb);
    scoreK<<<100000, 256, 0, stream>>>(Qb, Kb, src, scores);
    aggV<<<12504, 256, 0, stream>>>(Vb, src, scores, out);
}